// Round 1
// baseline (708.947 us; speedup 1.0000x reference)
//
#include <hip/hip_runtime.h>
#include <stdint.h>

// ---------------------------------------------------------------------------
// PrimaryCapsuleLayer on MI355X.
//   out0: capsules [B, 32, 16] fp32 = [ (x_scalar@W_s+b_s)[B,32,8] | zeros[B,32,8] ]
//   out1: x_vector [B, 128, 3] fp32 (verbatim copy)
// GEMM done in bf16 MFMA (16x16x32); harness tolerance is bf16-floor.
// ---------------------------------------------------------------------------

typedef __attribute__((ext_vector_type(8))) short bf8_t;   // 8 bf16 (4 VGPRs)
typedef __attribute__((ext_vector_type(4))) float f4_t;    // MFMA C/D

#define K_DIM 256
#define N_OUT 256

// fp32 -> bf16 bits, round-to-nearest-even (inputs are finite randoms)
static __device__ __forceinline__ short f2bf(float f) {
    union { float f; uint32_t u; } v; v.f = f;
    uint32_t r = v.u + 0x7FFFu + ((v.u >> 16) & 1u);
    return (short)(r >> 16);
}

// ---------------------------------------------------------------------------
// Swizzle W_s [K=256][N=256] fp32 row-major into B-fragment order, bf16:
//   swz[ ((c*16 + t)*64 + lane)*8 + j ] = bf16( W[c*32 + (lane>>4)*8 + j][t*16 + (lane&15)] )
// so the GEMM kernel's B fragment is one coalesced 16B load per lane.
// 8192 threads total.
// ---------------------------------------------------------------------------
__global__ void swizzle_W_kernel(const float* __restrict__ W, short* __restrict__ swz) {
    int id = blockIdx.x * 256 + threadIdx.x;       // 0..8191
    int l = id & 63;
    int t = (id >> 6) & 15;
    int c = id >> 10;                              // 0..7
    int n = t * 16 + (l & 15);
    int kbase = c * 32 + ((l >> 4) << 3);
    bf8_t v;
#pragma unroll
    for (int j = 0; j < 8; j++)
        v[j] = f2bf(W[(size_t)(kbase + j) * N_OUT + n]);
    *(bf8_t*)(swz + (size_t)id * 8) = v;
}

// ---------------------------------------------------------------------------
// GEMM + interleave + zero-fill. Block = 256 threads = 4 waves; each wave
// computes a 16-row x 256-col strip; block covers 64 rows.
// MFMA layouts (HW-verified, cdna_hip_programming.md §3):
//   A[m=lane&15][k=quad*8+j], B[k=quad*8+j][n=lane&15],
//   C/D: col=lane&15, row=quad*4+reg.
// Epilogue stages results in padded LDS so global stores are coalesced float4
// covering the full [8 results | 8 zeros] interleaved row.
// ---------------------------------------------------------------------------
__global__ __launch_bounds__(256, 2) void caps_gemm_kernel(
    const float* __restrict__ X,      // [B, 256]
    const short* __restrict__ swzW,   // swizzled bf16 W
    const float* __restrict__ bias,   // [256]
    float* __restrict__ out)          // [B, 512] (caps region)
{
    __shared__ __align__(16) float lds[4][16][260];   // 260: pad to dodge bank conflicts

    const int wave = threadIdx.x >> 6;
    const int lane = threadIdx.x & 63;
    const int col  = lane & 15;
    const int quad = lane >> 4;
    const int m0   = blockIdx.x * 64 + wave * 16;

    f4_t acc[16];
#pragma unroll
    for (int t = 0; t < 16; t++) acc[t] = (f4_t){0.f, 0.f, 0.f, 0.f};

    const float* xrow = X + (size_t)(m0 + col) * K_DIM + quad * 8;

#pragma unroll
    for (int c = 0; c < 8; c++) {
        const float4 a0 = *(const float4*)(xrow + c * 32);
        const float4 a1 = *(const float4*)(xrow + c * 32 + 4);
        bf8_t af;
        af[0] = f2bf(a0.x); af[1] = f2bf(a0.y); af[2] = f2bf(a0.z); af[3] = f2bf(a0.w);
        af[4] = f2bf(a1.x); af[5] = f2bf(a1.y); af[6] = f2bf(a1.z); af[7] = f2bf(a1.w);
        const short* bp = swzW + ((size_t)(c * 16) * 64 + lane) * 8;
#pragma unroll
        for (int t = 0; t < 16; t++) {
            bf8_t bf = *(const bf8_t*)(bp + (size_t)t * 64 * 8);
            acc[t] = __builtin_amdgcn_mfma_f32_16x16x32_bf16(af, bf, acc[t], 0, 0, 0);
        }
    }

    // bias + stage to LDS (wave-private region; barrier below covers x-wave reads)
#pragma unroll
    for (int t = 0; t < 16; t++) {
        float bv = bias[t * 16 + col];
#pragma unroll
        for (int r = 0; r < 4; r++)
            lds[wave][quad * 4 + r][t * 16 + col] = acc[t][r] + bv;
    }
    __syncthreads();

    // Coalesced store: block writes 64 rows x 128 float4 (512 floats/row).
    // Row layout: cap c occupies float4s [4c..4c+3]; parts 0,1 = results,
    // parts 2,3 = zeros.
    float4* out4 = (float4*)out;
    const size_t rowg0 = (size_t)blockIdx.x * 64;
#pragma unroll
    for (int i = 0; i < 32; i++) {
        int linear = i * 256 + threadIdx.x;
        int f   = linear & 127;        // float4 index within row
        int row = linear >> 7;         // 0..63 within block
        int part = f & 3;
        int cap  = f >> 2;
        float4 v;
        if (part < 2) {
            v = *(const float4*)&lds[row >> 4][row & 15][cap * 8 + part * 4];
        } else {
            v = make_float4(0.f, 0.f, 0.f, 0.f);
        }
        out4[(rowg0 + row) * 128 + f] = v;
    }
}

// ---------------------------------------------------------------------------
// x_vector pass-through, float4 grid-stride.
// ---------------------------------------------------------------------------
__global__ void copy_vec_kernel(const float4* __restrict__ src,
                                float4* __restrict__ dst, long n4) {
    long i = (long)blockIdx.x * blockDim.x + threadIdx.x;
    long stride = (long)gridDim.x * blockDim.x;
    for (; i < n4; i += stride) dst[i] = src[i];
}

extern "C" void kernel_launch(void* const* d_in, const int* in_sizes, int n_in,
                              void* d_out, int out_size, void* d_ws, size_t ws_size,
                              hipStream_t stream) {
    const float* x_scalar = (const float*)d_in[0];   // [B,256]
    const float* x_vector = (const float*)d_in[1];   // [B,128,3]
    const float* W_s      = (const float*)d_in[2];   // [256,256]
    const float* b_s      = (const float*)d_in[3];   // [256]
    // d_in[4], d_in[5] (W_v, b_v) are dead: e3nn TP(1e x 0e -> 0e) has no CG path.

    const int B = in_sizes[0] / K_DIM;               // 131072
    short* swz = (short*)d_ws;                       // needs 128 KiB

    swizzle_W_kernel<<<32, 256, 0, stream>>>(W_s, swz);
    caps_gemm_kernel<<<B / 64, 256, 0, stream>>>(x_scalar, swz, b_s, (float*)d_out);

    const long n4 = (long)in_sizes[1] / 4;           // 12,582,912 float4s
    float* vout = (float*)d_out + (size_t)B * 512;
    copy_vec_kernel<<<4096, 256, 0, stream>>>((const float4*)x_vector,
                                              (float4*)vout, n4);
}